// Round 1
// baseline (1338.256 us; speedup 1.0000x reference)
//
#include <hip/hip_runtime.h>
#include <stdint.h>
#include <math.h>

// EncoderSRNN: T=127 steps, BSZ=32 independent items, HDIM=256, SDIM=128, SSZ=128.
// Key algebra: buf never output; inp_t = sum_k w_t[k] * E2H[t-k] with w a 128-float
// scalar recurrence (pads are exactly zero since emb_W[PAD]=0). One WG per batch item.

#define T_STEPS 127
#define SSZc 128
#define SDc 128
#define HDc 256

// flat f32 output offsets (outputs, hid, stack, acts, top_elems)
#define OUT_OFF   0
#define HID_OFF   1040384
#define STACK_OFF 1048576
#define ACTS_OFF  1572864
#define TE_OFF    1580992

// ws layout: uint4-packed bf16 transposed weights, then packed E2H
//  uint4 [0,8192):      W_e2h^T   (K=256 x 256 out)
//  uint4 [8192,16384):  W_s2h^T
//  uint4 [16384,24576): W_h2h^T
//  uint4 [24576,28672): W_h2s^T   (K=256 x 128 out)
//  uint4 [28672,32768): W_s2u^T
//  uint  [131072, 131072+262144): E2Hpk[b][r2][j]  (pairs of rows 2r2,2r2+1 as bf16x2)
// total ws use: 1.5 MB

__device__ __forceinline__ unsigned pack2(float a, float b){
  unsigned ua = __float_as_uint(a), ub = __float_as_uint(b);
  ua = (ua + 0x7fffu + ((ua>>16)&1u)) >> 16;   // RNE bf16
  ub = (ub + 0x7fffu + ((ub>>16)&1u)) >> 16;
  return ua | (ub<<16);
}
__device__ __forceinline__ float blo(unsigned u){ return __uint_as_float(u<<16); }
__device__ __forceinline__ float bhi(unsigned u){ return __uint_as_float(u & 0xffff0000u); }

__global__ void prep_pack(const float* __restrict__ We2h, const float* __restrict__ Ws2h,
                          const float* __restrict__ Wh2h, const float* __restrict__ Wh2s,
                          const float* __restrict__ Ws2u, uint4* __restrict__ out4){
  int gid = blockIdx.x*256 + threadIdx.x;   // 32768 threads total
  const float* S; int i8, j;
  if (gid < 24576){
    int m = gid >> 13; S = (m==0)? We2h : (m==1)? Ws2h : Wh2h;
    int l = gid & 8191; i8 = l >> 8; j = l & 255;
  } else {
    int l = gid - 24576; int m = l >> 12; S = (m==0)? Wh2s : Ws2u;
    int ll = l & 4095; i8 = ll >> 7; j = ll & 127;
  }
  const float* p = S + j*256 + i8*8;        // W[j][8*i8 .. 8*i8+7]
  uint4 r;
  r.x = pack2(p[0], p[1]); r.y = pack2(p[2], p[3]);
  r.z = pack2(p[4], p[5]); r.w = pack2(p[6], p[7]);
  out4[gid] = r;
}

// E2H[r,b,:] = emb_W[inputs[r,b],:] @ W_e2h^T   (bf16 weights, fp32 acc, bf16 out pairs)
// block = (r2, bg): rows {2r2,2r2+1} x batch {4bg..4bg+3}
__global__ void prep_e2h(const int* __restrict__ inputs, const float* __restrict__ embW,
                         const uint4* __restrict__ wt4, unsigned* __restrict__ e2hpk){
  __shared__ float emb[8][256];
  int tid = threadIdx.x;
  int r2 = blockIdx.x >> 3, bg = blockIdx.x & 7;
  for (int q=0;q<8;q++){
    int rr = q >> 2, bb = q & 3;
    int tok = inputs[(2*r2+rr)*32 + bg*4+bb];
    emb[q][tid] = embW[tok*256 + tid];
  }
  __syncthreads();
  float acc[8] = {0.f,0.f,0.f,0.f,0.f,0.f,0.f,0.f};
  for (int i8=0;i8<32;i8++){
    uint4 u = wt4[i8*256 + tid];
    unsigned uu[4] = {u.x,u.y,u.z,u.w};
    #pragma unroll
    for (int q4=0;q4<4;q4++){
      float lo = blo(uu[q4]), hi = bhi(uu[q4]);
      int i = i8*8 + q4*2;
      #pragma unroll
      for (int q=0;q<8;q++)
        acc[q] += emb[q][i]*lo + emb[q][i+1]*hi;
    }
  }
  int bbase = (bg*4)*8192 + r2*256 + tid;
  #pragma unroll
  for (int bb=0;bb<4;bb++)
    e2hpk[bbase + bb*8192] = pack2(acc[bb], acc[4+bb]);  // (row 2r2, row 2r2+1)
}

__global__ __launch_bounds__(256, 1)
void srnn_main(const unsigned* __restrict__ wsu,
               const float* __restrict__ b_e2h, const float* __restrict__ b_s2h,
               const float* __restrict__ b_h2h, const float* __restrict__ Wh2i,
               const float* __restrict__ b_h2i, const float* __restrict__ b_h2s,
               const float* __restrict__ b_s2u, const float* __restrict__ empty_el,
               float* __restrict__ out)
{
  __shared__ __align__(16) float stack_s[SSZc*SDc];      // 64 KB
  __shared__ __align__(16) unsigned e2h_s[32*256];       // 32 KB (row-pairs bf16x2)
  __shared__ __align__(16) float hid_s[2][HDc];
  __shared__ __align__(16) float s_s[2][HDc];            // tops (rows 0,1 concat)
  __shared__ float wbuf[2][192];                         // 64 zero-pad + w[0..127]
  __shared__ float pv_s[SDc], uv_s[SDc], empty_s[SDc];
  __shared__ float part[12];                             // 4 waves x 3 inst partials

  const int tid = threadIdx.x;
  const int b   = blockIdx.x;
  const int d   = tid & 127;
  const int grp = tid >> 7;                 // 0: even stack rows, 1: odd rows

  const uint4* s2h4 = ((const uint4*)wsu) + 8192;
  const uint4* h2h4 = ((const uint4*)wsu) + 16384;
  const uint4* h2s4 = ((const uint4*)wsu) + 24576;
  const uint4* s2u4 = ((const uint4*)wsu) + 28672;
  const unsigned* e2hg = wsu + 131072 + b*8192;

  for (int q=0;q<32;q++) e2h_s[q*256+tid] = e2hg[q*256+tid];
  float emp = empty_el[d];
  if (grp==0) empty_s[d] = emp;
  for (int q=0;q<64;q++) stack_s[q*256+tid] = emp;   // all rows = empty_elem
  hid_s[0][tid]=0.f; hid_s[1][tid]=0.f;
  s_s[0][tid]=emp;
  if (tid<192){ wbuf[0][tid] = (tid==64)?1.f:0.f; wbuf[1][tid]=0.f; }
  float rb_ih = b_e2h[tid] + b_s2h[tid];
  float rb_hh = b_h2h[tid];
  float rb_pu = (grp==0)? b_h2s[d] : b_s2u[d];
  float rW0 = Wh2i[tid], rW1 = Wh2i[256+tid], rW2 = Wh2i[512+tid];
  float bi0 = b_h2i[0], bi1 = b_h2i[1], bi2 = b_h2i[2];
  __syncthreads();

  int cur = 0;
  for (int t=0; t<T_STEPS; ++t){
    const float* wc = wbuf[cur];
    float acc_ih = rb_ih, acc_hp = rb_hh;

    // inp_proj: sum over buffer coefficient window (rows > t hit the zero pad)
    #pragma unroll 8
    for (int r2=0;r2<32;r2++){
      unsigned u = e2h_s[r2*256+tid];
      acc_ih += wc[64+t-2*r2]*blo(u) + wc[63+t-2*r2]*bhi(u);
    }
    const float4* sc4 = (const float4*)s_s[cur];
    const float4* hc4 = (const float4*)hid_s[cur];
    #pragma unroll 4
    for (int i8=0;i8<32;i8++){
      uint4 uA = s2h4[i8*256+tid];
      uint4 uB = h2h4[i8*256+tid];
      float4 sa = sc4[2*i8], sb = sc4[2*i8+1];
      float4 ha = hc4[2*i8], hb = hc4[2*i8+1];
      acc_ih += sa.x*blo(uA.x)+sa.y*bhi(uA.x)+sa.z*blo(uA.y)+sa.w*bhi(uA.y)
              + sb.x*blo(uA.z)+sb.y*bhi(uA.z)+sb.z*blo(uA.w)+sb.w*bhi(uA.w);
      acc_hp += ha.x*blo(uB.x)+ha.y*bhi(uB.x)+ha.z*blo(uB.y)+ha.w*bhi(uB.y)
              + hb.x*blo(uB.z)+hb.y*bhi(uB.z)+hb.z*blo(uB.w)+hb.w*bhi(uB.w);
    }
    float hn = fmaxf(acc_hp + acc_ih, 0.f);
    hid_s[cur^1][tid] = hn;
    out[OUT_OFF + t*8192 + b*256 + tid] = hn;
    if (t == T_STEPS-1) out[HID_OFF + b*256 + tid] = hn;

    // inst = ihid @ W_h2i^T + b : per-thread partials, wave reduce, 4 partials to LDS
    float p0 = acc_ih*rW0, p1 = acc_ih*rW1, p2 = acc_ih*rW2;
    #pragma unroll
    for (int o=32;o>=1;o>>=1){
      p0 += __shfl_xor(p0,o);
      p1 += __shfl_xor(p1,o);
      p2 += __shfl_xor(p2,o);
    }
    if ((tid&63)==0){ int w6=tid>>6; part[w6*3+0]=p0; part[w6*3+1]=p1; part[w6*3+2]=p2; }
    __syncthreads();                                   // S_b
    float i0 = bi0+part[0]+part[3]+part[6]+part[9];
    float i1 = bi1+part[1]+part[4]+part[7]+part[10];
    float gi = bi2+part[2]+part[5]+part[8]+part[11];
    float mx = fmaxf(i0,i1);
    float e0 = expf(i0-mx), e1 = expf(i1-mx);
    float inv = 1.f/(e0+e1);
    float act0=e0*inv, act1=e1*inv;
    float gamma = 1.f + log1pf(expf(gi));
    float a0 = powf(act0,gamma), a1 = powf(act1,gamma);
    float sden = a0+a1+1e-16f;
    float pp = a0/sden, pq = a1/sden;                  // redundant per thread (cheap)
    if (tid==0){ out[ACTS_OFF + t*64 + b*2 + 0] = pp;
                 out[ACTS_OFF + t*64 + b*2 + 1] = pq; }

    // push_val (grp0, needs new hid) / u_val (grp1, needs old tops); w-recurrence on grp0
    {
      float accp = rb_pu;
      const float4* vin4 = (grp==0)? (const float4*)hid_s[cur^1] : (const float4*)s_s[cur];
      const uint4*  wmat = (grp==0)? h2s4 : s2u4;
      #pragma unroll 4
      for (int i8=0;i8<32;i8++){
        uint4 u = wmat[i8*128 + d];
        float4 va = vin4[2*i8], vb = vin4[2*i8+1];
        accp += va.x*blo(u.x)+va.y*bhi(u.x)+va.z*blo(u.y)+va.w*bhi(u.y)
              + vb.x*blo(u.z)+vb.y*bhi(u.z)+vb.z*blo(u.w)+vb.w*bhi(u.w);
      }
      if (grp==0){
        pv_s[d] = fmaxf(accp,0.f);
        wbuf[cur^1][64+d] = pp*wc[64+d] + pq*wc[63+d];   // w_{t+1}[k]=pp*w[k]+pq*w[k-1]
      } else {
        uv_s[d] = fmaxf(accp,0.f);
      }
    }
    __syncthreads();                                   // S_d

    // stack: new[0]=pp*pv+pq*uv; new[i]=pp*old[i-1]+pq*old[i+1]; new[127]=pp*old[126]+pq*empty
    float v[64];
    if (grp==0){
      v[0] = pp*pv_s[d] + pq*uv_s[d];
      out[TE_OFF + t*4096 + b*128 + d] = v[0];
      float prev = stack_s[1*128 + d];
      #pragma unroll
      for (int rr=1;rr<64;rr++){
        float nxt = stack_s[(2*rr+1)*128 + d];
        v[rr] = pp*prev + pq*nxt;
        prev = nxt;
      }
    } else {
      float prev = stack_s[d];
      #pragma unroll
      for (int rr=0;rr<63;rr++){
        float nxt = stack_s[(2*rr+2)*128 + d];
        v[rr] = pp*prev + pq*nxt;
        prev = nxt;
      }
      v[63] = pp*prev + pq*empty_s[d];
    }
    __syncthreads();                                   // S_e (all reads done)
    if (grp==0){ s_s[cur^1][d] = v[0]; } else { s_s[cur^1][128+d] = v[0]; }
    #pragma unroll
    for (int rr=0;rr<64;rr++) stack_s[(2*rr+grp)*128 + d] = v[rr];
    __syncthreads();                                   // S_f (end of step)
    cur ^= 1;
  }
  for (int q=0;q<64;q++){
    int idx = q*256+tid;
    out[STACK_OFF + b*16384 + idx] = stack_s[idx];
  }
}

extern "C" void kernel_launch(void* const* d_in, const int* in_sizes, int n_in,
                              void* d_out, int out_size, void* d_ws, size_t ws_size,
                              hipStream_t stream){
  const int*   inputs = (const int*)d_in[0];
  const float* embW   = (const float*)d_in[1];
  const float* We2h   = (const float*)d_in[2];
  const float* b_e2h  = (const float*)d_in[3];
  const float* Ws2h   = (const float*)d_in[4];
  const float* b_s2h  = (const float*)d_in[5];
  const float* Wh2h   = (const float*)d_in[6];
  const float* b_h2h  = (const float*)d_in[7];
  const float* Wh2i   = (const float*)d_in[8];
  const float* b_h2i  = (const float*)d_in[9];
  const float* Wh2s   = (const float*)d_in[10];
  const float* b_h2s  = (const float*)d_in[11];
  const float* Ws2u   = (const float*)d_in[12];
  const float* b_s2u  = (const float*)d_in[13];
  const float* empty  = (const float*)d_in[14];
  unsigned* wsu = (unsigned*)d_ws;

  prep_pack<<<dim3(128), dim3(256), 0, stream>>>(We2h, Ws2h, Wh2h, Wh2s, Ws2u, (uint4*)wsu);
  prep_e2h<<<dim3(256), dim3(256), 0, stream>>>(inputs, embW, (const uint4*)wsu, wsu + 131072);
  srnn_main<<<dim3(32), dim3(256), 0, stream>>>(wsu, b_e2h, b_s2h, b_h2h, Wh2i, b_h2i,
                                                b_h2s, b_s2u, empty, (float*)d_out);
}

// Round 2
// 1060.158 us; speedup vs baseline: 1.2623x; 1.2623x over previous
//
#include <hip/hip_runtime.h>
#include <stdint.h>
#include <math.h>

// EncoderSRNN: T=127 steps, BSZ=32 items, HDIM=256, SDIM=128, SSZ=128.
// One WG (1024 threads) per item. All GEMV weights register-resident as f16,
// v_dot2_f32_f16 (2 MAC/inst, f32 acc). Stack f32 in LDS. buf recurrence
// collapsed to 128-coeff window over precomputed E2H (emb@We2h^T) since
// emb_W[PAD]==0 rows vanish.

#define T_STEPS 127

// flat f32 output offsets (outputs, hid, stack, acts, top_elems)
#define OUT_OFF   0
#define HID_OFF   1040384
#define STACK_OFF 1048576
#define ACTS_OFF  1572864
#define TE_OFF    1580992

// ws layout (uint4 granularity for weight blobs):
//  uint4 [0,16384):      W1 = s2h (tid<512) / h2h (tid>=512), per-thread 16 uint4
//  uint4 [16384,20480):  W3 = h2s, per-thread 4 uint4
//  uint4 [20480,24576):  W2 = s2u, per-thread 4 uint4
//  uint4 [24576,32768):  W0 = We2h^T packed [k-chunk][j] for prep_e2h
//  uint  [131072,393216): E2H f16-pairs per item: [b][r2*256+j] = (row2r2,row2r2+1)
#define E2H_OFF_U 131072

typedef _Float16 h2 __attribute__((ext_vector_type(2)));

__device__ __forceinline__ unsigned packh2(float a, float b){
  h2 v; v.x = (_Float16)a; v.y = (_Float16)b;
  return __builtin_bit_cast(unsigned, v);
}
__device__ __forceinline__ float h2loF(unsigned u){ h2 v = __builtin_bit_cast(h2,u); return (float)v.x; }
__device__ __forceinline__ float h2hiF(unsigned u){ h2 v = __builtin_bit_cast(h2,u); return (float)v.y; }

#if __has_builtin(__builtin_amdgcn_fdot2)
__device__ __forceinline__ float fdot2(unsigned a, unsigned b, float c){
  return __builtin_amdgcn_fdot2(__builtin_bit_cast(h2,a), __builtin_bit_cast(h2,b), c, false);
}
#else
__device__ __forceinline__ float fdot2(unsigned a, unsigned b, float c){
  return c + h2loF(a)*h2loF(b) + h2hiF(a)*h2hiF(b);
}
#endif

// ---------------- prep: pack all weights to f16 blobs ----------------
__global__ void prep_pack(const float* __restrict__ We2h, const float* __restrict__ Ws2h,
                          const float* __restrict__ Wh2h, const float* __restrict__ Wh2s,
                          const float* __restrict__ Ws2u, uint4* __restrict__ out4){
  int gid = blockIdx.x*256 + threadIdx.x;    // [0, 32768)
  const float* src;
  if (gid < 16384){                          // W1: i in [0,16), t in [0,1024)
    int i = gid >> 10, t_ = gid & 1023;
    const float* S = (t_ < 512) ? Ws2h : Wh2h;
    int r = t_ & 511, jp = r >> 2, ks = r & 3;
    int j = 2*jp + (i >> 3);
    int k0 = ks*64 + (i & 7)*8;
    src = S + j*256 + k0;
  } else if (gid < 20480){                   // W3 (h2s): i in [0,4)
    int l = gid - 16384, i = l >> 10, t_ = l & 1023;
    int jr = t_ >> 4, kb = t_ & 15;
    int j = 2*jr + (i >> 1);
    int k0 = kb*16 + (i & 1)*8;
    src = Wh2s + j*256 + k0;
  } else if (gid < 24576){                   // W2 (s2u)
    int l = gid - 20480, i = l >> 10, t_ = l & 1023;
    int jr = t_ >> 4, kb = t_ & 15;
    int j = 2*jr + (i >> 1);
    int k0 = kb*16 + (i & 1)*8;
    src = Ws2u + j*256 + k0;
  } else {                                   // W0: [k-chunk i8][j]
    int l = gid - 24576;
    int i8 = l >> 8, j = l & 255;
    src = We2h + j*256 + i8*8;
  }
  uint4 r4;
  r4.x = packh2(src[0], src[1]); r4.y = packh2(src[2], src[3]);
  r4.z = packh2(src[4], src[5]); r4.w = packh2(src[6], src[7]);
  out4[gid] = r4;
}

// ---------------- prep: E2H = emb @ We2h^T, f16 row-pairs ----------------
__global__ void prep_e2h(const int* __restrict__ inputs, const float* __restrict__ embW,
                         const uint4* __restrict__ w04, unsigned* __restrict__ e2hpk){
  __shared__ float emb[8][256];
  int tid = threadIdx.x;
  int r2 = blockIdx.x >> 3, bg = blockIdx.x & 7;
  for (int q=0;q<8;q++){
    int rr = q >> 2, bb = q & 3;
    int tok = inputs[(2*r2+rr)*32 + bg*4+bb];
    emb[q][tid] = embW[tok*256 + tid];
  }
  __syncthreads();
  float acc[8] = {0.f,0.f,0.f,0.f,0.f,0.f,0.f,0.f};
  for (int i8=0;i8<32;i8++){
    uint4 u = w04[i8*256 + tid];
    unsigned uu[4] = {u.x,u.y,u.z,u.w};
    #pragma unroll
    for (int c=0;c<4;c++){
      float lo = h2loF(uu[c]), hi = h2hiF(uu[c]);
      int k = i8*8 + c*2;
      #pragma unroll
      for (int q=0;q<8;q++)
        acc[q] += emb[q][k]*lo + emb[q][k+1]*hi;
    }
  }
  int base = (bg*4)*8192 + r2*256 + tid;
  #pragma unroll
  for (int bb=0;bb<4;bb++)
    e2hpk[base + bb*8192] = packh2(acc[bb], acc[4+bb]);  // (row 2r2, row 2r2+1)
}

// ---------------- main sequential kernel ----------------
__global__ __launch_bounds__(1024, 1)
void srnn_main(const uint4* __restrict__ ws4, const unsigned* __restrict__ wsu,
               const float* __restrict__ b_e2h, const float* __restrict__ b_s2h,
               const float* __restrict__ b_h2h, const float* __restrict__ Wh2i,
               const float* __restrict__ b_h2i, const float* __restrict__ b_h2s,
               const float* __restrict__ b_s2u, const float* __restrict__ empty_el,
               float* __restrict__ out)
{
  __shared__ __align__(16) float    stk_s[128*132];     // stack f32, row stride 132
  __shared__ __align__(16) unsigned e2h_s[32*258];      // f16 pairs, stride 258
  __shared__ __align__(16) unsigned s_pk[128];          // tops packed f16 (row0|row1)
  __shared__ __align__(16) unsigned hid_pk[128];        // hid packed f16
  __shared__ __align__(16) float    pv_s[128], uv_s[128];
  __shared__ __align__(16) float    accih[256], acchp[256];
  __shared__ __align__(16) float    emptyf_s[128];
  __shared__ float    wbuf[2][192];
  __shared__ unsigned pkwc[32];
  __shared__ float    partsum[12];
  __shared__ float    pp_s, pq_s;

  const int tid = threadIdx.x;
  const int b   = blockIdx.x;
  const int aside = tid >> 9;           // phase A: 0=ih(s2h), 1=hp(h2h)
  const int ar  = tid & 511;
  const int ajp = ar >> 2;              // output pair 0..127
  const int aks = ar & 3;               // K-split 4 (K=64 each)
  const int jr  = tid >> 4;             // phase B output pair 0..63
  const int ksb = tid & 15;             // phase B K-split 16 (K=16 each)
  const int rgx = tid >> 3;             // stack row 0..127
  const int du8 = tid & 7;              // stack col group (16 floats)

  // ---- preload weights into registers ----
  uint4 w1r[16], w3r[4], w2r[4];
  #pragma unroll
  for (int i=0;i<16;i++) w1r[i] = ws4[i*1024 + tid];
  #pragma unroll
  for (int i=0;i<4;i++)  w3r[i] = ws4[16384 + i*1024 + tid];
  #pragma unroll
  for (int i=0;i<4;i++)  w2r[i] = ws4[20480 + i*1024 + tid];

  float bA0=0.f, bA1=0.f;
  if (aks==0){
    int j0 = 2*ajp;
    if (aside==0){ bA0 = b_e2h[j0]+b_s2h[j0]; bA1 = b_e2h[j0+1]+b_s2h[j0+1]; }
    else         { bA0 = b_h2h[j0];           bA1 = b_h2h[j0+1]; }
  }
  float bH0=0.f,bH1=0.f,bU0=0.f,bU1=0.f;
  if (ksb==0){ bH0=b_h2s[2*jr]; bH1=b_h2s[2*jr+1]; bU0=b_s2u[2*jr]; bU1=b_s2u[2*jr+1]; }
  float rW0=0.f,rW1=0.f,rW2=0.f;
  if (tid<256){ rW0=Wh2i[tid]; rW1=Wh2i[256+tid]; rW2=Wh2i[512+tid]; }
  const float bi0=b_h2i[0], bi1=b_h2i[1], bi2=b_h2i[2];

  // ---- init LDS state ----
  const unsigned* e2hg = wsu + E2H_OFF_U + b*8192;
  #pragma unroll
  for (int q=0;q<8;q++){
    int idx = q*1024 + tid;
    e2h_s[(idx>>8)*258 + (idx&255)] = e2hg[idx];
  }
  {
    int c0 = du8*16;
    #pragma unroll
    for (int q=0;q<4;q++){
      float4 e = *(const float4*)&empty_el[c0 + q*4];
      *(float4*)&stk_s[rgx*132 + c0 + q*4] = e;
    }
  }
  if (tid < 128){
    emptyf_s[tid] = empty_el[tid];
    hid_pk[tid] = 0u;
    int cu = tid & 63;
    s_pk[tid] = packh2(empty_el[2*cu], empty_el[2*cu+1]);
  }
  if (tid < 192){ wbuf[0][tid] = (tid==64)?1.f:0.f; wbuf[1][tid]=0.f; }
  if (tid < 32)  pkwc[tid] = (tid==0)? packh2(1.f,0.f) : 0u;
  __syncthreads();

  int cur = 0;
  for (int t=0;t<T_STEPS;++t){
    // ================= Phase A: ihid (s2h+inp) & hid-pre (h2h) =================
    {
      const unsigned* act = aside ? hid_pk : s_pk;
      const uint4* act4 = ((const uint4*)act) + aks*8;
      float x0 = 0.f, x1 = 0.f;
      if (aside==0){
        #pragma unroll
        for (int q=0;q<8;q++){
          int r2 = aks*8 + q;
          unsigned cw = pkwc[r2];
          uint2 e = *(const uint2*)&e2h_s[r2*258 + 2*ajp];
          x0 = fdot2(cw, e.x, x0);
          x1 = fdot2(cw, e.y, x1);
        }
      }
      #pragma unroll
      for (int i=0;i<8;i++){
        uint4 A  = act4[i];
        uint4 Wa = w1r[i], Wb = w1r[8+i];
        x0 = fdot2(A.x,Wa.x,x0); x0 = fdot2(A.y,Wa.y,x0);
        x0 = fdot2(A.z,Wa.z,x0); x0 = fdot2(A.w,Wa.w,x0);
        x1 = fdot2(A.x,Wb.x,x1); x1 = fdot2(A.y,Wb.y,x1);
        x1 = fdot2(A.z,Wb.z,x1); x1 = fdot2(A.w,Wb.w,x1);
      }
      x0 += __shfl_xor(x0,1); x0 += __shfl_xor(x0,2);
      x1 += __shfl_xor(x1,1); x1 += __shfl_xor(x1,2);
      if (aks==0){
        float* dst = aside ? acchp : accih;
        dst[2*ajp]   = x0 + bA0;
        dst[2*ajp+1] = x1 + bA1;
      }
    }
    __syncthreads();                                   // B1

    // ---- hid update + inst partials ----
    if (tid < 128){
      float2 ih2 = *(const float2*)&accih[2*tid];
      float2 hp2 = *(const float2*)&acchp[2*tid];
      float hn0 = fmaxf(ih2.x+hp2.x, 0.f);
      float hn1 = fmaxf(ih2.y+hp2.y, 0.f);
      hid_pk[tid] = packh2(hn0,hn1);
      *(float2*)&out[OUT_OFF + t*8192 + b*256 + 2*tid] = make_float2(hn0,hn1);
      if (t==T_STEPS-1) *(float2*)&out[HID_OFF + b*256 + 2*tid] = make_float2(hn0,hn1);
    }
    if (tid < 256){
      float v = accih[tid];
      float p0=v*rW0, p1=v*rW1, p2=v*rW2;
      #pragma unroll
      for (int o=32;o>=1;o>>=1){ p0+=__shfl_xor(p0,o); p1+=__shfl_xor(p1,o); p2+=__shfl_xor(p2,o); }
      if ((tid&63)==0){ int w=tid>>6; partsum[w*3]=p0; partsum[w*3+1]=p1; partsum[w*3+2]=p2; }
    }
    __syncthreads();                                   // B2

    // ---- softmax/gating on wave 0 (overlaps with Phase B of other waves) ----
    if (tid < 64){
      float i0 = bi0+partsum[0]+partsum[3]+partsum[6]+partsum[9];
      float i1 = bi1+partsum[1]+partsum[4]+partsum[7]+partsum[10];
      float gi = bi2+partsum[2]+partsum[5]+partsum[8]+partsum[11];
      float mx = fmaxf(i0,i1);
      float e0 = expf(i0-mx), e1 = expf(i1-mx);
      float inv = 1.f/(e0+e1);
      float act0 = e0*inv, act1 = e1*inv;
      float gamma = 1.f + log1pf(expf(gi));
      float A0 = powf(act0,gamma), A1 = powf(act1,gamma);
      float sden = A0+A1+1e-16f;
      float ppv = A0/sden, pqv = A1/sden;
      if (tid==0){
        pp_s = ppv; pq_s = pqv;
        *(float2*)&out[ACTS_OFF + t*64 + b*2] = make_float2(ppv,pqv);
      }
    }

    // ================= Phase B: h2s (new hid) & s2u (old tops) =================
    {
      const uint4* hact = ((const uint4*)hid_pk) + ksb*2;
      const uint4* sact = ((const uint4*)s_pk)   + ksb*2;
      uint4 H0 = hact[0], H1 = hact[1];
      uint4 S0 = sact[0], S1 = sact[1];
      float h0=0.f,h1=0.f,u0=0.f,u1=0.f;
      h0=fdot2(H0.x,w3r[0].x,h0); h0=fdot2(H0.y,w3r[0].y,h0); h0=fdot2(H0.z,w3r[0].z,h0); h0=fdot2(H0.w,w3r[0].w,h0);
      h0=fdot2(H1.x,w3r[1].x,h0); h0=fdot2(H1.y,w3r[1].y,h0); h0=fdot2(H1.z,w3r[1].z,h0); h0=fdot2(H1.w,w3r[1].w,h0);
      h1=fdot2(H0.x,w3r[2].x,h1); h1=fdot2(H0.y,w3r[2].y,h1); h1=fdot2(H0.z,w3r[2].z,h1); h1=fdot2(H0.w,w3r[2].w,h1);
      h1=fdot2(H1.x,w3r[3].x,h1); h1=fdot2(H1.y,w3r[3].y,h1); h1=fdot2(H1.z,w3r[3].z,h1); h1=fdot2(H1.w,w3r[3].w,h1);
      u0=fdot2(S0.x,w2r[0].x,u0); u0=fdot2(S0.y,w2r[0].y,u0); u0=fdot2(S0.z,w2r[0].z,u0); u0=fdot2(S0.w,w2r[0].w,u0);
      u0=fdot2(S1.x,w2r[1].x,u0); u0=fdot2(S1.y,w2r[1].y,u0); u0=fdot2(S1.z,w2r[1].z,u0); u0=fdot2(S1.w,w2r[1].w,u0);
      u1=fdot2(S0.x,w2r[2].x,u1); u1=fdot2(S0.y,w2r[2].y,u1); u1=fdot2(S0.z,w2r[2].z,u1); u1=fdot2(S0.w,w2r[2].w,u1);
      u1=fdot2(S1.x,w2r[3].x,u1); u1=fdot2(S1.y,w2r[3].y,u1); u1=fdot2(S1.z,w2r[3].z,u1); u1=fdot2(S1.w,w2r[3].w,u1);
      #pragma unroll
      for (int o=8;o>=1;o>>=1){
        h0+=__shfl_xor(h0,o); h1+=__shfl_xor(h1,o);
        u0+=__shfl_xor(u0,o); u1+=__shfl_xor(u1,o);
      }
      if (ksb==0){
        pv_s[2*jr]   = fmaxf(h0+bH0,0.f);
        pv_s[2*jr+1] = fmaxf(h1+bH1,0.f);
        uv_s[2*jr]   = fmaxf(u0+bU0,0.f);
        uv_s[2*jr+1] = fmaxf(u1+bU1,0.f);
      }
    }
    __syncthreads();                                   // B3
    const float pp = pp_s, pq = pq_s;

    // ================= Stack update (f32, in-place with S_e) =================
    {
      const float* up = (rgx==0)? pv_s : &stk_s[(rgx-1)*132];
      const float* dn = (rgx==0)? uv_s : ((rgx==127)? emptyf_s : &stk_s[(rgx+1)*132]);
      int c0 = du8*16;
      float nn[16];
      #pragma unroll
      for (int q=0;q<4;q++){
        float4 u4 = *(const float4*)&up[c0+q*4];
        float4 d4 = *(const float4*)&dn[c0+q*4];
        nn[q*4+0] = pp*u4.x + pq*d4.x;
        nn[q*4+1] = pp*u4.y + pq*d4.y;
        nn[q*4+2] = pp*u4.z + pq*d4.z;
        nn[q*4+3] = pp*u4.w + pq*d4.w;
      }
      // coefficient recurrence for the collapsed buf (w) + next-step packed pairs
      if (tid < 128){
        int k = 64+tid;
        wbuf[cur^1][k] = pp*wbuf[cur][k] + pq*wbuf[cur][k-1];
      } else if (tid < 160){
        int r2 = tid-128;
        int k1 = 65 + t - 2*r2;
        float wa = wbuf[cur][k1], wb2 = wbuf[cur][k1-1], wc2 = wbuf[cur][k1-2];
        pkwc[r2] = packh2(pp*wa+pq*wb2, pp*wb2+pq*wc2);
      }
      __syncthreads();                                 // S_e
      float* dst = &stk_s[rgx*132 + c0];
      #pragma unroll
      for (int q=0;q<4;q++)
        *(float4*)&dst[q*4] = make_float4(nn[q*4],nn[q*4+1],nn[q*4+2],nn[q*4+3]);
      if (rgx==0){
        #pragma unroll
        for (int q=0;q<4;q++)
          *(float4*)&out[TE_OFF + t*4096 + b*128 + c0 + q*4] =
            make_float4(nn[q*4],nn[q*4+1],nn[q*4+2],nn[q*4+3]);
        #pragma unroll
        for (int q=0;q<8;q++) s_pk[du8*8+q] = packh2(nn[2*q], nn[2*q+1]);
      } else if (rgx==1){
        #pragma unroll
        for (int q=0;q<8;q++) s_pk[64+du8*8+q] = packh2(nn[2*q], nn[2*q+1]);
      }
    }
    __syncthreads();                                   // S_f
    cur ^= 1;
  }

  // ---- final stack output ----
  {
    int c0 = du8*16;
    const float* row = &stk_s[rgx*132 + c0];
    float* dst = out + STACK_OFF + b*16384 + rgx*128 + c0;
    #pragma unroll
    for (int q=0;q<4;q++)
      *(float4*)&dst[q*4] = *(const float4*)&row[q*4];
  }
}

extern "C" void kernel_launch(void* const* d_in, const int* in_sizes, int n_in,
                              void* d_out, int out_size, void* d_ws, size_t ws_size,
                              hipStream_t stream){
  const int*   inputs = (const int*)d_in[0];
  const float* embW   = (const float*)d_in[1];
  const float* We2h   = (const float*)d_in[2];
  const float* b_e2h  = (const float*)d_in[3];
  const float* Ws2h   = (const float*)d_in[4];
  const float* b_s2h  = (const float*)d_in[5];
  const float* Wh2h   = (const float*)d_in[6];
  const float* b_h2h  = (const float*)d_in[7];
  const float* Wh2i   = (const float*)d_in[8];
  const float* b_h2i  = (const float*)d_in[9];
  const float* Wh2s   = (const float*)d_in[10];
  const float* b_h2s  = (const float*)d_in[11];
  const float* Ws2u   = (const float*)d_in[12];
  const float* b_s2u  = (const float*)d_in[13];
  const float* empty  = (const float*)d_in[14];
  unsigned* wsu = (unsigned*)d_ws;

  prep_pack<<<dim3(128), dim3(256), 0, stream>>>(We2h, Ws2h, Wh2h, Wh2s, Ws2u, (uint4*)wsu);
  prep_e2h<<<dim3(256), dim3(256), 0, stream>>>(inputs, embW, ((const uint4*)wsu)+24576, wsu + E2H_OFF_U);
  srnn_main<<<dim3(32), dim3(1024), 0, stream>>>((const uint4*)wsu, (const unsigned*)wsu,
                                                 b_e2h, b_s2h, b_h2h, Wh2i, b_h2i,
                                                 b_h2s, b_s2u, empty, (float*)d_out);
}

// Round 3
// 896.370 us; speedup vs baseline: 1.4930x; 1.1827x over previous
//
#include <hip/hip_runtime.h>
#include <stdint.h>
#include <math.h>

// EncoderSRNN: T=127 steps, BSZ=32 items, HDIM=256, SDIM=128, SSZ=128.
// One WG (1024 threads = 16 waves) per item, 1 block/CU. All GEMV weights
// register-resident as f16 (96 VGPR/thread), v_dot2_f32_f16. Stack f32 in LDS,
// column-parallel conflict-free update. buf recurrence collapsed to a 128-coeff
// scalar window over precomputed E2H (emb@We2h^T) since emb_W[PAD]==0.

#define T_STEPS 127

// flat f32 output offsets (outputs, hid, stack, acts, top_elems)
#define OUT_OFF   0
#define HID_OFF   1040384
#define STACK_OFF 1048576
#define ACTS_OFF  1572864
#define TE_OFF    1580992

// ws layout (uint4 granularity for weight blobs):
//  uint4 [0,16384):      W1 = s2h (tid<512) / h2h (tid>=512), per-thread 16 uint4
//  uint4 [16384,20480):  W3 = h2s, per-thread 4 uint4
//  uint4 [20480,24576):  W2 = s2u, per-thread 4 uint4
//  uint4 [24576,32768):  W0 = We2h^T packed [k-chunk][j] for prep_e2h
//  uint  [131072,393216): E2H f16-pairs per item: [b][r2*256+j] = (row2r2,row2r2+1)
#define E2H_OFF_U 131072

typedef _Float16 h2 __attribute__((ext_vector_type(2)));

__device__ __forceinline__ unsigned packh2(float a, float b){
  h2 v; v.x = (_Float16)a; v.y = (_Float16)b;
  return __builtin_bit_cast(unsigned, v);
}
__device__ __forceinline__ float h2loF(unsigned u){ h2 v = __builtin_bit_cast(h2,u); return (float)v.x; }
__device__ __forceinline__ float h2hiF(unsigned u){ h2 v = __builtin_bit_cast(h2,u); return (float)v.y; }

#if __has_builtin(__builtin_amdgcn_fdot2)
__device__ __forceinline__ float fdot2(unsigned a, unsigned b, float c){
  return __builtin_amdgcn_fdot2(__builtin_bit_cast(h2,a), __builtin_bit_cast(h2,b), c, false);
}
#else
__device__ __forceinline__ float fdot2(unsigned a, unsigned b, float c){
  return c + h2loF(a)*h2loF(b) + h2hiF(a)*h2hiF(b);
}
#endif

// chunked (bank-staggered) layout for packed act vectors: logical uint u ->
// physical 12*(u>>3) + (u&7).  16 chunks x 12 uints = 192 uints.
#define CHOFF(u) (12*((u)>>3) + ((u)&7))

// ---------------- prep: pack all weights to f16 blobs ----------------
__global__ void prep_pack(const float* __restrict__ We2h, const float* __restrict__ Ws2h,
                          const float* __restrict__ Wh2h, const float* __restrict__ Wh2s,
                          const float* __restrict__ Ws2u, uint4* __restrict__ out4){
  int gid = blockIdx.x*256 + threadIdx.x;    // [0, 32768)
  const float* src;
  if (gid < 16384){                          // W1: i in [0,16), t in [0,1024)
    int i = gid >> 10, t_ = gid & 1023;
    const float* S = (t_ < 512) ? Ws2h : Wh2h;
    int r = t_ & 511, jp = r >> 2, ks = r & 3;
    int j = 2*jp + (i >> 3);
    int k0 = ks*64 + (i & 7)*8;
    src = S + j*256 + k0;
  } else if (gid < 20480){                   // W3 (h2s): i in [0,4)
    int l = gid - 16384, i = l >> 10, t_ = l & 1023;
    int jr = t_ >> 4, kb = t_ & 15;
    int j = 2*jr + (i >> 1);
    int k0 = kb*16 + (i & 1)*8;
    src = Wh2s + j*256 + k0;
  } else if (gid < 24576){                   // W2 (s2u)
    int l = gid - 20480, i = l >> 10, t_ = l & 1023;
    int jr = t_ >> 4, kb = t_ & 15;
    int j = 2*jr + (i >> 1);
    int k0 = kb*16 + (i & 1)*8;
    src = Ws2u + j*256 + k0;
  } else {                                   // W0: [k-chunk i8][j]
    int l = gid - 24576;
    int i8 = l >> 8, j = l & 255;
    src = We2h + j*256 + i8*8;
  }
  uint4 r4;
  r4.x = packh2(src[0], src[1]); r4.y = packh2(src[2], src[3]);
  r4.z = packh2(src[4], src[5]); r4.w = packh2(src[6], src[7]);
  out4[gid] = r4;
}

// ---------------- prep: E2H = emb @ We2h^T, f16 row-pairs ----------------
__global__ void prep_e2h(const int* __restrict__ inputs, const float* __restrict__ embW,
                         const uint4* __restrict__ w04, unsigned* __restrict__ e2hpk){
  __shared__ float emb[8][256];
  int tid = threadIdx.x;
  int r2 = blockIdx.x >> 3, bg = blockIdx.x & 7;
  for (int q=0;q<8;q++){
    int rr = q >> 2, bb = q & 3;
    int tok = inputs[(2*r2+rr)*32 + bg*4+bb];
    emb[q][tid] = embW[tok*256 + tid];
  }
  __syncthreads();
  float acc[8] = {0.f,0.f,0.f,0.f,0.f,0.f,0.f,0.f};
  for (int i8=0;i8<32;i8++){
    uint4 u = w04[i8*256 + tid];
    unsigned uu[4] = {u.x,u.y,u.z,u.w};
    #pragma unroll
    for (int c=0;c<4;c++){
      float lo = h2loF(uu[c]), hi = h2hiF(uu[c]);
      int k = i8*8 + c*2;
      #pragma unroll
      for (int q=0;q<8;q++)
        acc[q] += emb[q][k]*lo + emb[q][k+1]*hi;
    }
  }
  int base = (bg*4)*8192 + r2*256 + tid;
  #pragma unroll
  for (int bb=0;bb<4;bb++)
    e2hpk[base + bb*8192] = packh2(acc[bb], acc[4+bb]);  // (row 2r2, row 2r2+1)
}

// ---------------- main sequential kernel ----------------
__global__ __attribute__((amdgpu_flat_work_group_size(1024,1024), amdgpu_waves_per_eu(4,4)))
void srnn_main(const uint4* __restrict__ ws4, const unsigned* __restrict__ wsu,
               const float* __restrict__ b_e2h, const float* __restrict__ b_s2h,
               const float* __restrict__ b_h2h, const float* __restrict__ Wh2i,
               const float* __restrict__ b_h2i, const float* __restrict__ b_h2s,
               const float* __restrict__ b_s2u, const float* __restrict__ empty_el,
               float* __restrict__ out)
{
  __shared__ __align__(16) float    stk_s[128*128];     // stack f32, 64 KB, no pad
  __shared__ __align__(16) unsigned e2h_s[32*258];      // f16 pairs, stride 258
  __shared__ __align__(16) unsigned s_pk[192];          // tops f16, chunk-staggered
  __shared__ __align__(16) unsigned hid_pk[192];        // hid f16, chunk-staggered
  __shared__ __align__(16) float    pv_s[128], uv_s[128];
  __shared__ __align__(16) float    accih[256], acchp[256];
  __shared__ __align__(16) float    emptyf_s[128];
  __shared__ float    wbuf[2][192];
  __shared__ unsigned pkwc[32];
  __shared__ float    partsum[12];
  __shared__ float    pp_s, pq_s;

  const int tid = threadIdx.x;
  const int b   = blockIdx.x;
  const int aside = tid >> 9;           // phase A: 0=ih(s2h), 1=hp(h2h)
  const int ar  = tid & 511;
  const int ajp = ar >> 2;              // output pair 0..127
  const int aks = ar & 3;               // K-split 4 (K=64 each)
  const int jr  = tid >> 4;             // phase B output pair 0..63
  const int ksb = tid & 15;             // phase B K-split 16 (K=16 each)
  const int g   = tid >> 6;             // stack: wave id = row-group (8 rows)
  const int cp  = tid & 63;             // stack: column pair

  // ---- preload weights into registers (96 VGPRs) ----
  uint4 w1r[16], w3r[4], w2r[4];
  #pragma unroll
  for (int i=0;i<16;i++) w1r[i] = ws4[i*1024 + tid];
  #pragma unroll
  for (int i=0;i<4;i++)  w3r[i] = ws4[16384 + i*1024 + tid];
  #pragma unroll
  for (int i=0;i<4;i++)  w2r[i] = ws4[20480 + i*1024 + tid];

  float bA0=0.f, bA1=0.f;
  if (aks==0){
    int j0 = 2*ajp;
    if (aside==0){ bA0 = b_e2h[j0]+b_s2h[j0]; bA1 = b_e2h[j0+1]+b_s2h[j0+1]; }
    else         { bA0 = b_h2h[j0];           bA1 = b_h2h[j0+1]; }
  }
  float bH0=0.f,bH1=0.f,bU0=0.f,bU1=0.f;
  if (ksb==0){ bH0=b_h2s[2*jr]; bH1=b_h2s[2*jr+1]; bU0=b_s2u[2*jr]; bU1=b_s2u[2*jr+1]; }
  float rW0=0.f,rW1=0.f,rW2=0.f;
  if (tid<256){ rW0=Wh2i[tid]; rW1=Wh2i[256+tid]; rW2=Wh2i[512+tid]; }
  const float bi0=b_h2i[0], bi1=b_h2i[1], bi2=b_h2i[2];

  // ---- init LDS state ----
  const unsigned* e2hg = wsu + E2H_OFF_U + b*8192;
  #pragma unroll
  for (int q=0;q<8;q++){
    int idx = q*1024 + tid;
    e2h_s[(idx>>8)*258 + (idx&255)] = e2hg[idx];
  }
  {
    float2 e2 = *(const float2*)&empty_el[2*cp];
    #pragma unroll
    for (int j=0;j<8;j++)
      *(float2*)&stk_s[(8*g+j)*128 + 2*cp] = e2;
  }
  if (tid < 128){
    emptyf_s[tid] = empty_el[tid];
    hid_pk[CHOFF(tid)] = 0u;
    int cu = tid & 63;
    s_pk[CHOFF(tid)] = packh2(empty_el[2*cu], empty_el[2*cu+1]);
  }
  if (tid < 192){ wbuf[0][tid] = (tid==64)?1.f:0.f; wbuf[1][tid]=0.f; }
  if (tid < 32)  pkwc[tid] = (tid==0)? packh2(1.f,0.f) : 0u;
  __syncthreads();

  int cur = 0;
  for (int t=0;t<T_STEPS;++t){
    // ============ Phase A: ihid (s2h + inp-window) & hid-pre (h2h) ============
    {
      const unsigned* act  = aside ? hid_pk : s_pk;
      const unsigned* actB = act + 48*aks;
      float x0 = 0.f, x1 = 0.f;
      if (aside==0){
        #pragma unroll
        for (int q=0;q<8;q++){
          int r2 = aks*8 + q;
          unsigned cw = pkwc[r2];
          uint2 e = *(const uint2*)&e2h_s[r2*258 + 2*ajp];
          x0 = fdot2(cw, e.x, x0);
          x1 = fdot2(cw, e.y, x1);
        }
      }
      #pragma unroll
      for (int i=0;i<8;i++){
        uint4 A  = *(const uint4*)(actB + 12*(i>>1) + 4*(i&1));
        uint4 Wa = w1r[i], Wb = w1r[8+i];
        x0 = fdot2(A.x,Wa.x,x0); x0 = fdot2(A.y,Wa.y,x0);
        x0 = fdot2(A.z,Wa.z,x0); x0 = fdot2(A.w,Wa.w,x0);
        x1 = fdot2(A.x,Wb.x,x1); x1 = fdot2(A.y,Wb.y,x1);
        x1 = fdot2(A.z,Wb.z,x1); x1 = fdot2(A.w,Wb.w,x1);
      }
      x0 += __shfl_xor(x0,1); x0 += __shfl_xor(x0,2);
      x1 += __shfl_xor(x1,1); x1 += __shfl_xor(x1,2);
      if (aks==0){
        float* dst = aside ? acchp : accih;
        *(float2*)&dst[2*ajp] = make_float2(x0 + bA0, x1 + bA1);
      }
    }
    __syncthreads();                                   // B1

    // ---- hid update + inst partials ----
    if (tid < 128){
      float2 ih2 = *(const float2*)&accih[2*tid];
      float2 hp2 = *(const float2*)&acchp[2*tid];
      float hn0 = fmaxf(ih2.x+hp2.x, 0.f);
      float hn1 = fmaxf(ih2.y+hp2.y, 0.f);
      hid_pk[CHOFF(tid)] = packh2(hn0,hn1);
      *(float2*)&out[OUT_OFF + t*8192 + b*256 + 2*tid] = make_float2(hn0,hn1);
      if (t==T_STEPS-1) *(float2*)&out[HID_OFF + b*256 + 2*tid] = make_float2(hn0,hn1);
    }
    if (tid < 256){
      float v = accih[tid];
      float p0=v*rW0, p1=v*rW1, p2=v*rW2;
      #pragma unroll
      for (int o=32;o>=1;o>>=1){ p0+=__shfl_xor(p0,o); p1+=__shfl_xor(p1,o); p2+=__shfl_xor(p2,o); }
      if ((tid&63)==0){ int w=tid>>6; partsum[w*3]=p0; partsum[w*3+1]=p1; partsum[w*3+2]=p2; }
    }
    __syncthreads();                                   // B2

    // ---- softmax/gating on wave 0 ----
    if (tid < 64){
      float i0 = bi0+partsum[0]+partsum[3]+partsum[6]+partsum[9];
      float i1 = bi1+partsum[1]+partsum[4]+partsum[7]+partsum[10];
      float gi = bi2+partsum[2]+partsum[5]+partsum[8]+partsum[11];
      float mx = fmaxf(i0,i1);
      float e0 = expf(i0-mx), e1 = expf(i1-mx);
      float inv = 1.f/(e0+e1);
      float act0 = e0*inv, act1 = e1*inv;
      float gamma = 1.f + log1pf(expf(gi));
      float A0 = powf(act0,gamma), A1 = powf(act1,gamma);
      float sden = A0+A1+1e-16f;
      float ppv = A0/sden, pqv = A1/sden;
      if (tid==0){
        pp_s = ppv; pq_s = pqv;
        *(float2*)&out[ACTS_OFF + t*64 + b*2] = make_float2(ppv,pqv);
      }
    }

    // ============ Phase B: h2s (new hid) & s2u (old tops) ============
    {
      const uint4* hptr = (const uint4*)(hid_pk + 12*ksb);
      const uint4* sptr = (const uint4*)(s_pk   + 12*ksb);
      uint4 H0 = hptr[0], H1 = hptr[1];
      uint4 S0 = sptr[0], S1 = sptr[1];
      float h0=0.f,h1=0.f,u0=0.f,u1=0.f;
      h0=fdot2(H0.x,w3r[0].x,h0); h0=fdot2(H0.y,w3r[0].y,h0); h0=fdot2(H0.z,w3r[0].z,h0); h0=fdot2(H0.w,w3r[0].w,h0);
      h0=fdot2(H1.x,w3r[1].x,h0); h0=fdot2(H1.y,w3r[1].y,h0); h0=fdot2(H1.z,w3r[1].z,h0); h0=fdot2(H1.w,w3r[1].w,h0);
      h1=fdot2(H0.x,w3r[2].x,h1); h1=fdot2(H0.y,w3r[2].y,h1); h1=fdot2(H0.z,w3r[2].z,h1); h1=fdot2(H0.w,w3r[2].w,h1);
      h1=fdot2(H1.x,w3r[3].x,h1); h1=fdot2(H1.y,w3r[3].y,h1); h1=fdot2(H1.z,w3r[3].z,h1); h1=fdot2(H1.w,w3r[3].w,h1);
      u0=fdot2(S0.x,w2r[0].x,u0); u0=fdot2(S0.y,w2r[0].y,u0); u0=fdot2(S0.z,w2r[0].z,u0); u0=fdot2(S0.w,w2r[0].w,u0);
      u0=fdot2(S1.x,w2r[1].x,u0); u0=fdot2(S1.y,w2r[1].y,u0); u0=fdot2(S1.z,w2r[1].z,u0); u0=fdot2(S1.w,w2r[1].w,u0);
      u1=fdot2(S0.x,w2r[2].x,u1); u1=fdot2(S0.y,w2r[2].y,u1); u1=fdot2(S0.z,w2r[2].z,u1); u1=fdot2(S0.w,w2r[2].w,u1);
      u1=fdot2(S1.x,w2r[3].x,u1); u1=fdot2(S1.y,w2r[3].y,u1); u1=fdot2(S1.z,w2r[3].z,u1); u1=fdot2(S1.w,w2r[3].w,u1);
      #pragma unroll
      for (int o=8;o>=1;o>>=1){
        h0+=__shfl_xor(h0,o); h1+=__shfl_xor(h1,o);
        u0+=__shfl_xor(u0,o); u1+=__shfl_xor(u1,o);
      }
      if (ksb==0){
        pv_s[2*jr]   = fmaxf(h0+bH0,0.f);
        pv_s[2*jr+1] = fmaxf(h1+bH1,0.f);
        uv_s[2*jr]   = fmaxf(u0+bU0,0.f);
        uv_s[2*jr+1] = fmaxf(u1+bU1,0.f);
      }
    }
    __syncthreads();                                   // B3
    const float pp = pp_s, pq = pq_s;

    // ============ Stack update: column-parallel, conflict-free ============
    {
      float2 w[10];                                    // rows 8g-1 .. 8g+8
      #pragma unroll
      for (int k=0;k<10;k++){
        int r = 8*g - 1 + k;
        if (r >= 0 && r <= 127)
          w[k] = *(const float2*)&stk_s[r*128 + 2*cp];
      }
      if (g == 15) w[9] = *(const float2*)&emptyf_s[2*cp];
      float2 pv2 = make_float2(0.f,0.f), uv2 = make_float2(0.f,0.f);
      if (g == 0){ pv2 = *(const float2*)&pv_s[2*cp]; uv2 = *(const float2*)&uv_s[2*cp]; }
      float2 nn[8];
      #pragma unroll
      for (int j=0;j<8;j++){
        nn[j].x = pp*w[j].x + pq*w[j+2].x;
        nn[j].y = pp*w[j].y + pq*w[j+2].y;
      }
      if (g == 0){
        nn[0].x = pp*pv2.x + pq*uv2.x;
        nn[0].y = pp*pv2.y + pq*uv2.y;
      }
      // coefficient recurrence for the collapsed buf + next-step packed pairs
      if (tid < 128){
        int k = 64+tid;
        wbuf[cur^1][k] = pp*wbuf[cur][k] + pq*wbuf[cur][k-1];
      } else if (tid < 160){
        int r2 = tid-128;
        int k1 = 65 + t - 2*r2;
        float wa = wbuf[cur][k1], wb2 = wbuf[cur][k1-1], wc2 = wbuf[cur][k1-2];
        pkwc[r2] = packh2(pp*wa+pq*wb2, pp*wb2+pq*wc2);
      }
      __syncthreads();                                 // S_e (all reads done)
      #pragma unroll
      for (int j=0;j<8;j++)
        *(float2*)&stk_s[(8*g+j)*128 + 2*cp] = nn[j];
      if (g == 0){
        *(float2*)&out[TE_OFF + t*4096 + b*128 + 2*cp] = nn[0];
        s_pk[CHOFF(cp)]      = packh2(nn[0].x, nn[0].y);
        s_pk[CHOFF(64+cp)]   = packh2(nn[1].x, nn[1].y);
      }
    }
    __syncthreads();                                   // S_f
    cur ^= 1;
  }

  // ---- final stack output ----
  #pragma unroll
  for (int j=0;j<8;j++){
    int r = 8*g + j;
    *(float2*)&out[STACK_OFF + b*16384 + r*128 + 2*cp] =
      *(const float2*)&stk_s[r*128 + 2*cp];
  }
}

extern "C" void kernel_launch(void* const* d_in, const int* in_sizes, int n_in,
                              void* d_out, int out_size, void* d_ws, size_t ws_size,
                              hipStream_t stream){
  const int*   inputs = (const int*)d_in[0];
  const float* embW   = (const float*)d_in[1];
  const float* We2h   = (const float*)d_in[2];
  const float* b_e2h  = (const float*)d_in[3];
  const float* Ws2h   = (const float*)d_in[4];
  const float* b_s2h  = (const float*)d_in[5];
  const float* Wh2h   = (const float*)d_in[6];
  const float* b_h2h  = (const float*)d_in[7];
  const float* Wh2i   = (const float*)d_in[8];
  const float* b_h2i  = (const float*)d_in[9];
  const float* Wh2s   = (const float*)d_in[10];
  const float* b_h2s  = (const float*)d_in[11];
  const float* Ws2u   = (const float*)d_in[12];
  const float* b_s2u  = (const float*)d_in[13];
  const float* empty  = (const float*)d_in[14];
  unsigned* wsu = (unsigned*)d_ws;

  prep_pack<<<dim3(128), dim3(256), 0, stream>>>(We2h, Ws2h, Wh2h, Wh2s, Ws2u, (uint4*)wsu);
  prep_e2h<<<dim3(256), dim3(256), 0, stream>>>(inputs, embW, ((const uint4*)wsu)+24576, wsu + E2H_OFF_U);
  srnn_main<<<dim3(32), dim3(1024), 0, stream>>>((const uint4*)wsu, (const unsigned*)wsu,
                                                 b_e2h, b_s2h, b_h2h, Wh2i, b_h2i,
                                                 b_h2s, b_s2u, empty, (float*)d_out);
}